// Round 1
// baseline (173.265 us; speedup 1.0000x reference)
//
#include <hip/hip_runtime.h>

// Degree-4 real spherical-harmonics encoding, 16 coefficients per 3D point.
// Memory-bound: 12 B in, 64 B out per point. Strategy: 4 points/thread so
// input is 3x float4 loads (fully coalesced) and output is 16x float4 stores
// (contiguous 256 B per thread).

__device__ __forceinline__ void sh16(float x, float y, float z,
                                     float4& o0, float4& o1,
                                     float4& o2, float4& o3) {
    const float xx = x * x, yy = y * y, zz = z * z;
    const float xy = x * y, yz = y * z, xz = x * z;

    o0.x = 0.28209479177387814f;                    // C0
    o0.y = -0.4886025119029199f * y;                // -C1*y
    o0.z =  0.4886025119029199f * z;                //  C1*z
    o0.w = -0.4886025119029199f * x;                // -C1*x

    o1.x =  1.0925484305920792f  * xy;              // C2[0]*xy
    o1.y = -1.0925484305920792f  * yz;              // C2[1]*yz
    o1.z =  0.31539156525252005f * (2.0f * zz - xx - yy); // C2[2]
    o1.w = -1.0925484305920792f  * xz;              // C2[3]*xz

    o2.x =  0.5462742152960396f  * (xx - yy);       // C2[4]
    o2.y = -0.5900435899266435f  * y * (3.0f * xx - yy);  // C3[0]
    o2.z =  2.890611442640554f   * xy * z;          // C3[1]
    o2.w = -0.4570457994644658f  * y * (4.0f * zz - xx - yy); // C3[2]

    o3.x =  0.3731763325901154f  * z * (2.0f * zz - 3.0f * xx - 3.0f * yy); // C3[3]
    o3.y = -0.4570457994644658f  * x * (4.0f * zz - xx - yy); // C3[4]
    o3.z =  1.445305721320277f   * z * (xx - yy);   // C3[5]
    o3.w = -0.5900435899266435f  * x * (xx - 3.0f * yy);      // C3[6]
}

__global__ __launch_bounds__(256)
void SHEncoder_53077205844617_kernel(const float* __restrict__ in,
                                     float* __restrict__ out,
                                     const int* __restrict__ size_ptr,
                                     int B) {
    const int t  = blockIdx.x * blockDim.x + threadIdx.x;
    const int p0 = t * 4;
    if (p0 >= B) return;

    const float inv = 1.0f / (float)(*size_ptr);   // uniform; scalar-cached
    float4* __restrict__ out4 = (float4*)out;

    if (p0 + 3 < B) {
        // Fast path: 4 whole points -> 3 coalesced float4 loads.
        const float4* __restrict__ in4 = (const float4*)in;
        const float4 a = in4[3 * t + 0];
        const float4 b = in4[3 * t + 1];
        const float4 c = in4[3 * t + 2];

        const float px[4] = {a.x, a.w, b.z, c.y};
        const float py[4] = {a.y, b.x, b.w, c.z};
        const float pz[4] = {a.z, b.y, c.x, c.w};

#pragma unroll
        for (int k = 0; k < 4; ++k) {
            float4 o0, o1, o2, o3;
            sh16(px[k] * inv, py[k] * inv, pz[k] * inv, o0, o1, o2, o3);
            const int base = 4 * (p0 + k);
            out4[base + 0] = o0;
            out4[base + 1] = o1;
            out4[base + 2] = o2;
            out4[base + 3] = o3;
        }
    } else {
        // Tail: scalar loads, still float4 stores.
        for (int p = p0; p < B; ++p) {
            const float x = in[3 * p + 0] * inv;
            const float y = in[3 * p + 1] * inv;
            const float z = in[3 * p + 2] * inv;
            float4 o0, o1, o2, o3;
            sh16(x, y, z, o0, o1, o2, o3);
            const int base = 4 * p;
            out4[base + 0] = o0;
            out4[base + 1] = o1;
            out4[base + 2] = o2;
            out4[base + 3] = o3;
        }
    }
}

extern "C" void kernel_launch(void* const* d_in, const int* in_sizes, int n_in,
                              void* d_out, int out_size, void* d_ws, size_t ws_size,
                              hipStream_t stream) {
    const float* in       = (const float*)d_in[0];
    const int*   size_ptr = (const int*)d_in[1];
    float*       out      = (float*)d_out;

    const int B       = in_sizes[0] / 3;
    const int nquads  = (B + 3) / 4;
    const int threads = 256;
    const int blocks  = (nquads + threads - 1) / threads;

    SHEncoder_53077205844617_kernel<<<blocks, threads, 0, stream>>>(in, out, size_ptr, B);
}

// Round 2
// 67.733 us; speedup vs baseline: 2.5581x; 2.5581x over previous
//
#include <hip/hip_runtime.h>

// Degree-4 SH encoding: 12 B in, 64 B out per point. Write-bound.
// Round-1 lesson: per-thread-contiguous 256B output blocks gave 2.4x HBM
// write amplification (WRITE_SIZE 650MB vs 268MB ideal) because each store
// instruction scattered 16B chunks at 256B stride (partial-line evictions).
// Fix: LDS transpose so every store instruction is lane-contiguous
// (64 lanes x 16B = 1KB complete lines per instruction).

#define ROUND_POINTS 256   // points per round == blockDim
#define ROUNDS       4     // rounds per block => 1024 points/block
#define LDS_STRIDE   20    // floats per point slot (16 + 4 pad): keeps every
                           // float4 slot 16B-aligned; lane stride 20 words puts
                           // 8 lanes per 4-bank set = structural minimum phases.

__device__ __forceinline__ void sh16(float x, float y, float z,
                                     float4& o0, float4& o1,
                                     float4& o2, float4& o3) {
    const float xx = x * x, yy = y * y, zz = z * z;
    const float xy = x * y, yz = y * z, xz = x * z;

    o0.x = 0.28209479177387814f;
    o0.y = -0.4886025119029199f * y;
    o0.z =  0.4886025119029199f * z;
    o0.w = -0.4886025119029199f * x;

    o1.x =  1.0925484305920792f  * xy;
    o1.y = -1.0925484305920792f  * yz;
    o1.z =  0.31539156525252005f * (2.0f * zz - xx - yy);
    o1.w = -1.0925484305920792f  * xz;

    o2.x =  0.5462742152960396f  * (xx - yy);
    o2.y = -0.5900435899266435f  * y * (3.0f * xx - yy);
    o2.z =  2.890611442640554f   * xy * z;
    o2.w = -0.4570457994644658f  * y * (4.0f * zz - xx - yy);

    o3.x =  0.3731763325901154f  * z * (2.0f * zz - 3.0f * xx - 3.0f * yy);
    o3.y = -0.4570457994644658f  * x * (4.0f * zz - xx - yy);
    o3.z =  1.445305721320277f   * z * (xx - yy);
    o3.w = -0.5900435899266435f  * x * (xx - 3.0f * yy);
}

__global__ __launch_bounds__(256)
void SHEncoder_53077205844617_kernel(const float* __restrict__ in,
                                     float* __restrict__ out,
                                     const int* __restrict__ size_ptr,
                                     int B) {
    __shared__ float sh[ROUND_POINTS * LDS_STRIDE];   // 20 KB

    const int t     = threadIdx.x;
    const int tile0 = blockIdx.x * (ROUND_POINTS * ROUNDS);
    const float inv = 1.0f / (float)(*size_ptr);      // uniform
    float4* __restrict__ out4 = (float4*)out;

    for (int j = 0; j < ROUNDS; ++j) {
        const int p = tile0 + j * ROUND_POINTS + t;   // this thread's point
        if (p < B) {
            const float x = in[3 * p + 0] * inv;
            const float y = in[3 * p + 1] * inv;
            const float z = in[3 * p + 2] * inv;
            float4 o0, o1, o2, o3;
            sh16(x, y, z, o0, o1, o2, o3);
            float4* s = (float4*)&sh[t * LDS_STRIDE]; // 80B slot, 16B aligned
            s[0] = o0; s[1] = o1; s[2] = o2; s[3] = o3;
        }
        __syncthreads();

        // Write the round's 256-point output chunk (1024 float4) with
        // lane-contiguous stores: instruction r covers contiguous 1 KB/wave.
        const int qbase = (tile0 + j * ROUND_POINTS) * 4;  // float4 index
        const int qlim  = B * 4;
#pragma unroll
        for (int r = 0; r < 4; ++r) {
            const int ql = t + r * ROUND_POINTS;  // 0..1023 within chunk
            const int pl = ql >> 2;               // local point
            const int c  = ql & 3;                // which float4 of the point
            const float4 v = *(const float4*)&sh[pl * LDS_STRIDE + 4 * c];
            const int qg = qbase + ql;
            if (qg < qlim) out4[qg] = v;
        }
        __syncthreads();   // protect sh reuse next round
    }
}

extern "C" void kernel_launch(void* const* d_in, const int* in_sizes, int n_in,
                              void* d_out, int out_size, void* d_ws, size_t ws_size,
                              hipStream_t stream) {
    const float* in       = (const float*)d_in[0];
    const int*   size_ptr = (const int*)d_in[1];
    float*       out      = (float*)d_out;

    const int B    = in_sizes[0] / 3;
    const int tile = ROUND_POINTS * ROUNDS;           // 1024 points per block
    const int blocks = (B + tile - 1) / tile;

    SHEncoder_53077205844617_kernel<<<blocks, 256, 0, stream>>>(in, out, size_ptr, B);
}